// Round 6
// baseline (1759.141 us; speedup 1.0000x reference)
//
#include <hip/hip_runtime.h>
#include <math.h>

#define N_NODES  100000
#define N_EDGES  3200000
#define N_GRAPHS 256
#define F        64

// bucketed counting sort params
#define BSHIFT   8
#define BNODES   256                    // nodes per bucket
#define NBKT     391                    // ceil(N_NODES / BNODES)
#define NCH      256                    // edge chunks
#define CHUNK    12500                  // edges per chunk (NCH*CHUNK == N_EDGES)

// JAX default gelu: approximate=True (tanh form), exact-path version
__device__ __forceinline__ float gelu_f(float x) {
    float x3 = x * x * x;
    float inner = 0.7978845608028654f * (x + 0.044715f * x3);
    return 0.5f * x * (1.0f + tanhf(inner));
}

// fast gelu: 0.5x(1+tanh(u)) = x*(1-rcp(exp2(2u*log2e)+1)); ~1ulp exp2/rcp
__device__ __forceinline__ float gelu_fast(float x) {
    const float c1 = 2.3022082232f;     // 2*log2(e)*0.7978845608
    const float c2 = 0.1029432407f;     // c1*0.044715
    float x2 = x * x;
    float t  = x * fmaf(c2, x2, c1);    // 2u*log2(e)
    float E  = __builtin_amdgcn_exp2f(t);          // v_exp_f32
    float r  = __builtin_amdgcn_rcpf(E + 1.0f);    // v_rcp_f32
    return fmaf(-x, r, x);              // x*(1-r): E->inf => x;  E->0 => ~0
}

// ---- pass 1: per-chunk LDS histogram over buckets -------------------------
__global__ void __launch_bounds__(256) k_bcount(const int* __restrict__ col,
                                                int* __restrict__ bcnt) {
    __shared__ int cnt[NBKT];
    for (int i = threadIdx.x; i < NBKT; i += 256) cnt[i] = 0;
    __syncthreads();
    int base = blockIdx.x * CHUNK;
    for (int i = threadIdx.x; i < CHUNK; i += 256)
        atomicAdd(&cnt[col[base + i] >> BSHIFT], 1);
    __syncthreads();
    for (int i = threadIdx.x; i < NBKT; i += 256)
        bcnt[i * NCH + blockIdx.x] = cnt[i];      // bucket-major
}

// ---- pass 2a: per-bucket scan of 256 chunk-counts (391 parallel blocks) ---
__global__ void __launch_bounds__(256) k_bscan_local(const int* __restrict__ bcnt,
                                                     int* __restrict__ brel,
                                                     int* __restrict__ btot) {
    __shared__ int sums[256];
    int b = blockIdx.x;
    int t = threadIdx.x;
    int c = bcnt[b * NCH + t];
    sums[t] = c;
    __syncthreads();
    for (int off = 1; off < 256; off <<= 1) {
        int v = 0;
        if (t >= off) v = sums[t - off];
        __syncthreads();
        if (t >= off) sums[t] += v;
        __syncthreads();
    }
    brel[b * NCH + t] = sums[t] - c;
    if (t == 255) btot[b] = sums[255];
}

// ---- pass 2b: scan 391 bucket totals --------------------------------------
__global__ void __launch_bounds__(512) k_bscan_base(const int* __restrict__ btot,
                                                    int* __restrict__ bbase) {
    __shared__ int sums[512];
    int t = threadIdx.x;
    int v0 = (t < NBKT) ? btot[t] : 0;
    sums[t] = v0;
    __syncthreads();
    for (int off = 1; off < 512; off <<= 1) {
        int v = 0;
        if (t >= off) v = sums[t - off];
        __syncthreads();
        if (t >= off) sums[t] += v;
        __syncthreads();
    }
    int excl = sums[t] - v0;
    if (t < NBKT) bbase[t] = excl;
    if (t == NBKT - 1) bbase[NBKT] = excl + v0;   // == N_EDGES
}

// ---- pass 3: scatter edges into bucket segments (LDS cursors) -------------
__global__ void __launch_bounds__(256) k_bscatter(const int* __restrict__ row,
                                                  const int* __restrict__ col,
                                                  const float* __restrict__ ew,
                                                  const int* __restrict__ brel,
                                                  const int* __restrict__ bbase,
                                                  unsigned long long* __restrict__ ebuf) {
    __shared__ int cur[NBKT];
    int ch = blockIdx.x;
    for (int i = threadIdx.x; i < NBKT; i += 256)
        cur[i] = bbase[i] + brel[i * NCH + ch];
    __syncthreads();
    int base = ch * CHUNK;
    for (int i = threadIdx.x; i < CHUNK; i += 256) {
        int c = col[base + i];
        int r = row[base + i];
        float w = ew[base + i];
        int bk = c >> BSHIFT;
        int p = atomicAdd(&cur[bk], 1);           // LDS atomic
        unsigned int hi = ((unsigned)(c & (BNODES - 1)) << 20) | (unsigned)r;
        ebuf[p] = ((unsigned long long)hi << 32) | (unsigned long long)__float_as_uint(w);
    }
}

// ---- pass 4: per-bucket degree via LDS atomics -> dinv, y=dinv*x ----------
__global__ void __launch_bounds__(256) k_deg(const unsigned long long* __restrict__ ebuf,
                                             const int* __restrict__ bbase,
                                             const float* __restrict__ x,
                                             float* __restrict__ dinv,
                                             float* __restrict__ y) {
    __shared__ float deg[BNODES];
    int b = blockIdx.x, t = threadIdx.x;
    deg[t] = 1.0f;                                // self-loop weight
    __syncthreads();
    int e0 = bbase[b], e1 = bbase[b + 1];
    for (int i = e0 + t; i < e1; i += 256) {
        unsigned long long v = ebuf[i];
        atomicAdd(&deg[(int)(v >> 52)], __uint_as_float((unsigned)v));
    }
    __syncthreads();
    int node = (b << BSHIFT) + t;
    if (node < N_NODES) {
        float di = rsqrtf(deg[t]);
        dinv[node] = di;
        y[node] = di * x[node];
    }
}

// ---- pass 5: layer-1 scalar agg via LDS atomics; sd = {s1, dinv} ----------
__global__ void __launch_bounds__(256) k_s1(const unsigned long long* __restrict__ ebuf,
                                            const int* __restrict__ bbase,
                                            const float* __restrict__ y,
                                            const float* __restrict__ dinv,
                                            float2* __restrict__ sd) {
    __shared__ float s[BNODES];
    int b = blockIdx.x, t = threadIdx.x;
    s[t] = 0.0f;
    __syncthreads();
    int e0 = bbase[b], e1 = bbase[b + 1];
    for (int i = e0 + t; i < e1; i += 256) {
        unsigned long long v = ebuf[i];
        int src = (int)((v >> 32) & 0xFFFFF);
        float w = __uint_as_float((unsigned)v);
        atomicAdd(&s[(int)(v >> 52)], w * y[src]);   // y gather: 400KB, L2-resident
    }
    __syncthreads();
    int node = (b << BSHIFT) + t;
    if (node < N_NODES) {
        float di = dinv[node];
        float s1v = (s[t] + y[node]) * di;
        sd[node] = make_float2(s1v, di);
    }
}

// ---- pass 6: layer-2 agg, gelu-row RECOMPUTE from scalar s1 ---------------
// a1[c,f] = dinv_c*( sum_e ew*dinv_src*g_f(s1_src) + dinv_c*g_f(s1_c) ),
// g_f(s) = gelu(s*W1[f]+b1[f]).  LDS acc[256][64], no gather of rows.
__global__ void __launch_bounds__(256) k_agg(const unsigned long long* __restrict__ ebuf,
                                             const int* __restrict__ bbase,
                                             const float2* __restrict__ sd,
                                             const float* __restrict__ W1,
                                             const float* __restrict__ b1,
                                             float* __restrict__ a1) {
    __shared__ float acc[BNODES * F];             // 64 KB
    int t = threadIdx.x;
    int lane = t & 63;
    int wv = t >> 6;
    float W1f = W1[lane], b1f = b1[lane];
    for (int i = t; i < BNODES * F; i += 256) acc[i] = 0.0f;
    __syncthreads();
    int b = blockIdx.x;
    int e0 = bbase[b], e1 = bbase[b + 1];
    for (int base = e0 + wv * 64; base < e1; base += 256) {
        int j = base + lane;
        float s1j = 0.0f, wdj = 0.0f;
        int clj = 0;
        if (j < e1) {
            unsigned long long v = ebuf[j];
            clj = (int)(v >> 52);
            int src = (int)((v >> 32) & 0xFFFFF);
            float2 sv = sd[src];                  // 8B gather, 800KB L2-resident
            s1j = sv.x;
            wdj = __uint_as_float((unsigned)v) * sv.y;   // ew*dinv_src
        }
        int cnt = min(64, e1 - base);
        for (int jj = 0; jj < cnt; jj++) {
            float s1b = __shfl(s1j, jj);
            float wdb = __shfl(wdj, jj);
            int   clb = __shfl(clj, jj);
            float g = gelu_fast(fmaf(s1b, W1f, b1f));
            atomicAdd(&acc[clb * F + lane], wdb * g);    // LDS atomic, 2-way bank alias (free)
        }
    }
    __syncthreads();
    // writeout + self term: each wave covers 64 targets
    for (int tt = wv * 64; tt < wv * 64 + 64; tt++) {
        int node = (b << BSHIFT) + tt;
        if (node >= N_NODES) break;
        float2 st = sd[node];
        float gs = gelu_fast(fmaf(st.x, W1f, b1f));
        float val = st.y * fmaf(st.y, gs, acc[tt * F + lane]);
        a1[(size_t)node * F + lane] = val;
    }
}

// ---- pass 7: fused [N,64]@[64,64]+bias+gelu and mean-pool accumulate ------
#define STRIP 128                                  // nodes per wave
__global__ void __launch_bounds__(256) k_h2pool(const float* __restrict__ a1,
                                                const float* __restrict__ W2,
                                                const float* __restrict__ b2,
                                                const int* __restrict__ batch,
                                                float* __restrict__ gsum,
                                                float* __restrict__ gcnt) {
    __shared__ float sW[F * F];
    __shared__ float sb[F];
    __shared__ float sa[4][F];
    for (int i = threadIdx.x; i < F * F; i += 256) sW[i] = W2[i];
    if (threadIdx.x < F) sb[threadIdx.x] = b2[threadIdx.x];
    __syncthreads();
    int lane = threadIdx.x & 63;
    int wv   = threadIdx.x >> 6;
    int gw   = blockIdx.x * 4 + wv;
    int n0 = gw * STRIP;
    if (n0 >= N_NODES) return;
    int n1 = min(n0 + STRIP, N_NODES);
    int curg = batch[n0];
    float run = 0.0f;
    int   rl  = 0;
    for (int n = n0; n < n1; n++) {
        int g = batch[n];
        if (g != curg) {
            atomicAdd(&gsum[curg * F + lane], run);
            if (lane == 0) atomicAdd(&gcnt[curg], (float)rl);
            run = 0.0f; rl = 0; curg = g;
        }
        sa[wv][lane] = a1[(size_t)n * F + lane];  // same-wave write/read
        float acc = sb[lane];
#pragma unroll
        for (int k = 0; k < F; k++) acc = fmaf(sa[wv][k], sW[k * F + lane], acc);
        run += gelu_fast(acc);
        rl++;
    }
    atomicAdd(&gsum[curg * F + lane], run);
    if (lane == 0) atomicAdd(&gcnt[curg], (float)rl);
}

// ---- final MLP: one wave per graph ----------------------------------------
__global__ void __launch_bounds__(256) k_final(const float* __restrict__ gsum,
                                               const float* __restrict__ gcnt,
                                               const float* __restrict__ fc1W,
                                               const float* __restrict__ fc1b,
                                               const float* __restrict__ fc2W,
                                               const float* __restrict__ fc2b,
                                               float* __restrict__ out) {
    __shared__ float sm[4][F];
    int lane = threadIdx.x & 63;
    int wv   = threadIdx.x >> 6;
    int g = blockIdx.x * 4 + wv;
    if (g >= N_GRAPHS) return;
    float c = gcnt[g];
    float m = gsum[g * F + lane] / fmaxf(c, 1.0f);
    sm[wv][lane] = m;
    float o = 0.0f;
    if (lane < 32) {
        float acc = fc1b[lane];
#pragma unroll
        for (int k = 0; k < F; k++) acc = fmaf(sm[wv][k], fc1W[k * 32 + lane], acc);
        o = gelu_f(acc) * fc2W[lane];
    }
    for (int off = 32; off; off >>= 1) o += __shfl_down(o, off);
    if (lane == 0) out[g] = o + fc2b[0];
}

// ---------------------------------------------------------------------------

extern "C" void kernel_launch(void* const* d_in, const int* in_sizes, int n_in,
                              void* d_out, int out_size, void* d_ws, size_t ws_size,
                              hipStream_t stream) {
    const float* x    = (const float*)d_in[0];
    const int*   ei   = (const int*)  d_in[1];   // [2, E]
    const float* ea   = (const float*)d_in[2];
    const int*   bat  = (const int*)  d_in[3];
    const float* W1   = (const float*)d_in[4];
    const float* b1   = (const float*)d_in[5];
    const float* W2   = (const float*)d_in[6];
    const float* b2   = (const float*)d_in[7];
    const float* fc1W = (const float*)d_in[8];
    const float* fc1b = (const float*)d_in[9];
    const float* fc2W = (const float*)d_in[10];
    const float* fc2b = (const float*)d_in[11];
    float* out = (float*)d_out;

    const int* row = ei;
    const int* col = ei + N_EDGES;

    size_t off = 0;
    auto alloc = [&](size_t bytes) -> void* {
        void* p = (char*)d_ws + off;
        off = (off + bytes + 255) & ~(size_t)255;
        return p;
    };
    int*   bcnt  = (int*)alloc((size_t)NBKT * NCH * 4);            // 400 KB
    int*   brel  = (int*)alloc((size_t)NBKT * NCH * 4);            // 400 KB
    int*   btot  = (int*)alloc((size_t)NBKT * 4);
    int*   bbase = (int*)alloc((size_t)(NBKT + 1) * 4);
    unsigned long long* ebuf = (unsigned long long*)alloc((size_t)N_EDGES * 8); // 25.6 MB
    float* dinv  = (float*)alloc((size_t)N_NODES * 4);
    float* yv    = (float*)alloc((size_t)N_NODES * 4);
    float2* sd   = (float2*)alloc((size_t)N_NODES * 8);            // 800 KB
    float* a1    = (float*)alloc((size_t)N_NODES * F * 4);         // 25.6 MB
    float* gsum  = (float*)alloc((size_t)N_GRAPHS * F * 4);
    float* gcnt  = (float*)alloc((size_t)N_GRAPHS * 4);
    (void)ws_size; (void)n_in; (void)in_sizes; (void)out_size;

    (void)hipMemsetAsync(gsum, 0, N_GRAPHS * F * 4, stream);
    (void)hipMemsetAsync(gcnt, 0, N_GRAPHS * 4,     stream);

    k_bcount     <<<NCH, 256, 0, stream>>>(col, bcnt);
    k_bscan_local<<<NBKT, 256, 0, stream>>>(bcnt, brel, btot);
    k_bscan_base <<<1, 512, 0, stream>>>(btot, bbase);
    k_bscatter   <<<NCH, 256, 0, stream>>>(row, col, ea, brel, bbase, ebuf);
    k_deg        <<<NBKT, 256, 0, stream>>>(ebuf, bbase, x, dinv, yv);
    k_s1         <<<NBKT, 256, 0, stream>>>(ebuf, bbase, yv, dinv, sd);
    k_agg        <<<NBKT, 256, 0, stream>>>(ebuf, bbase, sd, W1, b1, a1);
    {
        int waves = (N_NODES + STRIP - 1) / STRIP;        // 782
        k_h2pool <<<(waves + 3) / 4, 256, 0, stream>>>(a1, W2, b2, bat, gsum, gcnt);
    }
    k_final      <<<(N_GRAPHS + 3) / 4, 256, 0, stream>>>(gsum, gcnt, fc1W, fc1b, fc2W, fc2b, out);
}

// Round 7
// 491.688 us; speedup vs baseline: 3.5778x; 3.5778x over previous
//
#include <hip/hip_runtime.h>
#include <math.h>

#define N_NODES  100000
#define N_EDGES  3200000
#define N_GRAPHS 256
#define F        64

// bucketed counting sort params
#define BSHIFT   8
#define BNODES   256                    // nodes per bucket
#define NBKT     391                    // ceil(N_NODES / BNODES)
#define NCH      256                    // edge chunks
#define CHUNK    12500                  // edges per chunk (NCH*CHUNK == N_EDGES)
#define MAXB     9000                   // LDS-staged edges per bucket (avg 8192, sd ~90)

// JAX default gelu: approximate=True (tanh form), libm version (host-path accuracy)
__device__ __forceinline__ float gelu_f(float x) {
    float x3 = x * x * x;
    float inner = 0.7978845608028654f * (x + 0.044715f * x3);
    return 0.5f * x * (1.0f + tanhf(inner));
}

// fast gelu: 0.5x(1+tanh(u)) = x*(1-rcp(exp2(2u*log2e)+1)); ~1ulp exp2/rcp
__device__ __forceinline__ float gelu_fast(float x) {
    const float c1 = 2.3022082232f;     // 2*log2(e)*0.7978845608
    const float c2 = 0.1029432407f;     // c1*0.044715
    float x2 = x * x;
    float t  = x * fmaf(c2, x2, c1);    // 2u*log2(e)
    float E  = __builtin_amdgcn_exp2f(t);          // v_exp_f32
    float r  = __builtin_amdgcn_rcpf(E + 1.0f);    // v_rcp_f32
    return fmaf(-x, r, x);              // x*(1-r): E->inf => x;  E->0 => ~0
}

// ---- pass 1: per-chunk LDS histogram over buckets -------------------------
__global__ void __launch_bounds__(256) k_bcount(const int* __restrict__ col,
                                                int* __restrict__ bcnt) {
    __shared__ int cnt[NBKT];
    for (int i = threadIdx.x; i < NBKT; i += 256) cnt[i] = 0;
    __syncthreads();
    int base = blockIdx.x * CHUNK;
    for (int i = threadIdx.x; i < CHUNK; i += 256)
        atomicAdd(&cnt[col[base + i] >> BSHIFT], 1);
    __syncthreads();
    for (int i = threadIdx.x; i < NBKT; i += 256)
        bcnt[i * NCH + blockIdx.x] = cnt[i];      // bucket-major
}

// ---- pass 2a: per-bucket scan of 256 chunk-counts (391 parallel blocks) ---
__global__ void __launch_bounds__(256) k_bscan_local(const int* __restrict__ bcnt,
                                                     int* __restrict__ brel,
                                                     int* __restrict__ btot) {
    __shared__ int sums[256];
    int b = blockIdx.x;
    int t = threadIdx.x;
    int c = bcnt[b * NCH + t];
    sums[t] = c;
    __syncthreads();
    for (int off = 1; off < 256; off <<= 1) {
        int v = 0;
        if (t >= off) v = sums[t - off];
        __syncthreads();
        if (t >= off) sums[t] += v;
        __syncthreads();
    }
    brel[b * NCH + t] = sums[t] - c;
    if (t == 255) btot[b] = sums[255];
}

// ---- pass 2b: scan 391 bucket totals --------------------------------------
__global__ void __launch_bounds__(512) k_bscan_base(const int* __restrict__ btot,
                                                    int* __restrict__ bbase) {
    __shared__ int sums[512];
    int t = threadIdx.x;
    int v0 = (t < NBKT) ? btot[t] : 0;
    sums[t] = v0;
    __syncthreads();
    for (int off = 1; off < 512; off <<= 1) {
        int v = 0;
        if (t >= off) v = sums[t - off];
        __syncthreads();
        if (t >= off) sums[t] += v;
        __syncthreads();
    }
    int excl = sums[t] - v0;
    if (t < NBKT) bbase[t] = excl;
    if (t == NBKT - 1) bbase[NBKT] = excl + v0;   // == N_EDGES
}

// ---- pass 3: scatter edges into bucket segments (LDS cursors) -------------
__global__ void __launch_bounds__(256) k_bscatter(const int* __restrict__ row,
                                                  const int* __restrict__ col,
                                                  const float* __restrict__ ew,
                                                  const int* __restrict__ brel,
                                                  const int* __restrict__ bbase,
                                                  unsigned long long* __restrict__ ebuf) {
    __shared__ int cur[NBKT];
    int ch = blockIdx.x;
    for (int i = threadIdx.x; i < NBKT; i += 256)
        cur[i] = bbase[i] + brel[i * NCH + ch];
    __syncthreads();
    int base = ch * CHUNK;
    for (int i = threadIdx.x; i < CHUNK; i += 256) {
        int c = col[base + i];
        int r = row[base + i];
        float w = ew[base + i];
        int bk = c >> BSHIFT;
        int p = atomicAdd(&cur[bk], 1);           // LDS atomic
        unsigned int hi = ((unsigned)(c & (BNODES - 1)) << 20) | (unsigned)r;
        ebuf[p] = ((unsigned long long)hi << 32) | (unsigned long long)__float_as_uint(w);
    }
}

// ---- pass 4: per-bucket CSR finalize + deg/dinv/y, all in LDS -------------
__global__ void __launch_bounds__(256) k_bbuild(const unsigned long long* __restrict__ ebuf,
                                                const int* __restrict__ bbase,
                                                const float* __restrict__ x,
                                                unsigned long long* __restrict__ csr,
                                                int* __restrict__ offs,
                                                float* __restrict__ dinv,
                                                float* __restrict__ y) {
    __shared__ unsigned long long st[MAXB];
    __shared__ int   cnt[BNODES];
    __shared__ float deg[BNODES];
    __shared__ int   cur[BNODES];
    __shared__ int   sc[BNODES];
    int b = blockIdx.x;
    int t = threadIdx.x;
    int e0 = bbase[b];
    int e1 = bbase[b + 1];
    int len = e1 - e0;
    int sl = min(len, MAXB);
    cnt[t] = 0;
    deg[t] = 0.0f;
    for (int i = t; i < sl; i += 256) st[i] = ebuf[e0 + i];
    __syncthreads();
    for (int i = t; i < len; i += 256) {
        unsigned long long v = (i < MAXB) ? st[i] : ebuf[e0 + i];
        int cl = (int)(v >> 52);            // col_local
        float w = __uint_as_float((unsigned)v);
        atomicAdd(&cnt[cl], 1);
        atomicAdd(&deg[cl], w);
    }
    __syncthreads();
    int c = cnt[t];
    sc[t] = c;
    __syncthreads();
    for (int off = 1; off < 256; off <<= 1) {
        int v = 0;
        if (t >= off) v = sc[t - off];
        __syncthreads();
        if (t >= off) sc[t] += v;
        __syncthreads();
    }
    int loff = sc[t] - c;                   // exclusive prefix within bucket
    cur[t] = loff;
    int node = (b << BSHIFT) + t;
    if (node < N_NODES) {
        offs[node] = e0 + loff;
        float di = rsqrtf(deg[t] + 1.0f);   // +1 = self-loop weight
        dinv[node] = di;
        y[node] = di * x[node];
    }
    if (b == 0 && t == 0) offs[N_NODES] = N_EDGES;
    __syncthreads();
    for (int i = t; i < len; i += 256) {
        unsigned long long v = (i < MAXB) ? st[i] : ebuf[e0 + i];
        int cl = (int)(v >> 52);
        int p = atomicAdd(&cur[cl], 1);     // LDS atomic
        csr[e0 + p] = v;
    }
}

// ---- pass 5: layer-1 scalar agg (per-thread node); sd = {s1, dinv} --------
__global__ void __launch_bounds__(256) k_s1(const float* __restrict__ y,
                                            const float* __restrict__ dinv,
                                            const int* __restrict__ offs,
                                            const unsigned long long* __restrict__ csr,
                                            float2* __restrict__ sd) {
    int c = blockIdx.x * 256 + threadIdx.x;
    if (c >= N_NODES) return;
    int e0 = offs[c], e1 = offs[c + 1];
    float s = y[c];
    for (int j = e0; j < e1; j++) {
        unsigned long long v = csr[j];
        int src = (int)((v >> 32) & 0xFFFFF);
        float w = __uint_as_float((unsigned)v);
        s = fmaf(w, y[src], s);
    }
    sd[c] = make_float2(s * dinv[c], dinv[c]);
}

// ---- pass 6: layer-2 agg, one WAVE per target node, lane = feature --------
// a1[c,f] = dinv_c*( sum_e ew*dinv_src*g_f(s1_src) + dinv_c*g_f(s1_c) ),
// g_f(s) = gelu(s*W1[f]+b1[f]).  Register accumulate; wave-uniform 8B loads.
__global__ void __launch_bounds__(256) k_agg(const unsigned long long* __restrict__ csr,
                                             const int* __restrict__ offs,
                                             const float2* __restrict__ sd,
                                             const float* __restrict__ W1,
                                             const float* __restrict__ b1,
                                             float* __restrict__ a1) {
    int lane = threadIdx.x & 63;
    int node = (blockIdx.x * 256 + threadIdx.x) >> 6;   // grid sized exactly
    float W1f = W1[lane], b1f = b1[lane];
    int e0 = offs[node], e1 = offs[node + 1];
    float acc0 = 0.0f, acc1 = 0.0f;
    int j = e0;
    for (; j + 1 < e1; j += 2) {
        unsigned long long v0 = csr[j], v1 = csr[j + 1];
        float2 p0 = sd[(int)((v0 >> 32) & 0xFFFFF)];    // uniform 8B, L2-resident
        float2 p1 = sd[(int)((v1 >> 32) & 0xFFFFF)];
        float g0 = gelu_fast(fmaf(p0.x, W1f, b1f));
        float g1 = gelu_fast(fmaf(p1.x, W1f, b1f));
        acc0 = fmaf(__uint_as_float((unsigned)v0) * p0.y, g0, acc0);
        acc1 = fmaf(__uint_as_float((unsigned)v1) * p1.y, g1, acc1);
    }
    if (j < e1) {
        unsigned long long v0 = csr[j];
        float2 p0 = sd[(int)((v0 >> 32) & 0xFFFFF)];
        float g0 = gelu_fast(fmaf(p0.x, W1f, b1f));
        acc0 = fmaf(__uint_as_float((unsigned)v0) * p0.y, g0, acc0);
    }
    float2 st = sd[node];
    float gs = gelu_fast(fmaf(st.x, W1f, b1f));
    a1[(size_t)node * F + lane] = st.y * (acc0 + acc1 + st.y * gs);
}

// ---- pass 7: fused h2 matmul (+bias+gelu) and mean-pool; W2 in VGPRs ------
#define STRIP 32                                   // nodes per wave
__global__ void __launch_bounds__(256) k_h2pool(const float* __restrict__ a1,
                                                const float* __restrict__ W2,
                                                const float* __restrict__ b2,
                                                const int* __restrict__ batch,
                                                float* __restrict__ gsum,
                                                float* __restrict__ gcnt) {
    int lane = threadIdx.x & 63;
    int wv   = threadIdx.x >> 6;
    int gw   = blockIdx.x * 4 + wv;
    int n0 = gw * STRIP;
    if (n0 >= N_NODES) return;
    int n1 = min(n0 + STRIP, N_NODES);
    float w2r[F];                                  // column W2[:,lane] in regs
#pragma unroll
    for (int k = 0; k < F; k++) w2r[k] = W2[k * F + lane];
    float b2f = b2[lane];
    int curg = batch[n0];
    float run = 0.0f;
    int   rl  = 0;
    for (int n = n0; n < n1; n++) {
        int g = batch[n];
        if (g != curg) {
            atomicAdd(&gsum[curg * F + lane], run);
            if (lane == 0) atomicAdd(&gcnt[curg], (float)rl);
            run = 0.0f; rl = 0; curg = g;
        }
        const float4* rowp = (const float4*)(a1 + (size_t)n * F);
        float acc = b2f;
#pragma unroll
        for (int k4 = 0; k4 < F / 4; k4++) {
            float4 r = rowp[k4];                   // uniform address -> broadcast
            acc = fmaf(r.x, w2r[4 * k4 + 0], acc);
            acc = fmaf(r.y, w2r[4 * k4 + 1], acc);
            acc = fmaf(r.z, w2r[4 * k4 + 2], acc);
            acc = fmaf(r.w, w2r[4 * k4 + 3], acc);
        }
        run += gelu_fast(acc);
        rl++;
    }
    atomicAdd(&gsum[curg * F + lane], run);
    if (lane == 0) atomicAdd(&gcnt[curg], (float)rl);
}

// ---- final MLP: one wave per graph ----------------------------------------
__global__ void __launch_bounds__(256) k_final(const float* __restrict__ gsum,
                                               const float* __restrict__ gcnt,
                                               const float* __restrict__ fc1W,
                                               const float* __restrict__ fc1b,
                                               const float* __restrict__ fc2W,
                                               const float* __restrict__ fc2b,
                                               float* __restrict__ out) {
    __shared__ float sm[4][F];
    int lane = threadIdx.x & 63;
    int wv   = threadIdx.x >> 6;
    int g = blockIdx.x * 4 + wv;
    if (g >= N_GRAPHS) return;
    float c = gcnt[g];
    float m = gsum[g * F + lane] / fmaxf(c, 1.0f);
    sm[wv][lane] = m;
    float o = 0.0f;
    if (lane < 32) {
        float acc = fc1b[lane];
#pragma unroll
        for (int k = 0; k < F; k++) acc = fmaf(sm[wv][k], fc1W[k * 32 + lane], acc);
        o = gelu_f(acc) * fc2W[lane];
    }
    for (int off = 32; off; off >>= 1) o += __shfl_down(o, off);
    if (lane == 0) out[g] = o + fc2b[0];
}

// ---------------------------------------------------------------------------

extern "C" void kernel_launch(void* const* d_in, const int* in_sizes, int n_in,
                              void* d_out, int out_size, void* d_ws, size_t ws_size,
                              hipStream_t stream) {
    const float* x    = (const float*)d_in[0];
    const int*   ei   = (const int*)  d_in[1];   // [2, E]
    const float* ea   = (const float*)d_in[2];
    const int*   bat  = (const int*)  d_in[3];
    const float* W1   = (const float*)d_in[4];
    const float* b1   = (const float*)d_in[5];
    const float* W2   = (const float*)d_in[6];
    const float* b2   = (const float*)d_in[7];
    const float* fc1W = (const float*)d_in[8];
    const float* fc1b = (const float*)d_in[9];
    const float* fc2W = (const float*)d_in[10];
    const float* fc2b = (const float*)d_in[11];
    float* out = (float*)d_out;

    const int* row = ei;
    const int* col = ei + N_EDGES;

    size_t off = 0;
    auto alloc = [&](size_t bytes) -> void* {
        void* p = (char*)d_ws + off;
        off = (off + bytes + 255) & ~(size_t)255;
        return p;
    };
    int*   bcnt  = (int*)alloc((size_t)NBKT * NCH * 4);            // 400 KB
    int*   brel  = (int*)alloc((size_t)NBKT * NCH * 4);            // 400 KB
    int*   btot  = (int*)alloc((size_t)NBKT * 4);
    int*   bbase = (int*)alloc((size_t)(NBKT + 1) * 4);
    unsigned long long* ebuf = (unsigned long long*)alloc((size_t)N_EDGES * 8); // 25.6 MB
    unsigned long long* csr  = (unsigned long long*)alloc((size_t)N_EDGES * 8); // 25.6 MB
    int*   offs = (int*)  alloc((size_t)(N_NODES + 1) * 4);
    float* dinv = (float*)alloc((size_t)N_NODES * 4);
    float* yv   = (float*)alloc((size_t)N_NODES * 4);
    float2* sd  = (float2*)alloc((size_t)N_NODES * 8);             // 800 KB
    float* a1   = (float*)ebuf;                                    // alias: ebuf dead after k_bbuild
    float* gsum = (float*)alloc((size_t)N_GRAPHS * F * 4);
    float* gcnt = (float*)alloc((size_t)N_GRAPHS * 4);
    (void)ws_size; (void)n_in; (void)in_sizes; (void)out_size;

    (void)hipMemsetAsync(gsum, 0, N_GRAPHS * F * 4, stream);
    (void)hipMemsetAsync(gcnt, 0, N_GRAPHS * 4,     stream);

    k_bcount     <<<NCH, 256, 0, stream>>>(col, bcnt);
    k_bscan_local<<<NBKT, 256, 0, stream>>>(bcnt, brel, btot);
    k_bscan_base <<<1, 512, 0, stream>>>(btot, bbase);
    k_bscatter   <<<NCH, 256, 0, stream>>>(row, col, ea, brel, bbase, ebuf);
    k_bbuild     <<<NBKT, 256, 0, stream>>>(ebuf, bbase, x, csr, offs, dinv, yv);
    k_s1         <<<(N_NODES + 255) / 256, 256, 0, stream>>>(yv, dinv, offs, csr, sd);
    k_agg        <<<N_NODES / 4, 256, 0, stream>>>(csr, offs, sd, W1, b1, a1);   // 1 wave/node
    {
        int waves = (N_NODES + STRIP - 1) / STRIP;        // 3125
        k_h2pool <<<(waves + 3) / 4, 256, 0, stream>>>(a1, W2, b2, bat, gsum, gcnt);
    }
    k_final      <<<(N_GRAPHS + 3) / 4, 256, 0, stream>>>(gsum, gcnt, fc1W, fc1b, fc2W, fc2b, out);
}

// Round 8
// 388.752 us; speedup vs baseline: 4.5251x; 1.2648x over previous
//
#include <hip/hip_runtime.h>
#include <math.h>

#define N_NODES  100000
#define N_EDGES  3200000
#define N_GRAPHS 256
#define F        64

// bucketed counting sort params
#define BSHIFT   8
#define BNODES   256                    // nodes per bucket
#define NBKT     391                    // ceil(N_NODES / BNODES)
#define NCH      256                    // edge chunks
#define CHUNK    12500                  // edges per chunk (NCH*CHUNK == N_EDGES)
#define MAXB     9000                   // LDS-staged edges per bucket (avg 8192, sd ~90)

typedef _Float16 f16;
typedef __attribute__((ext_vector_type(4))) _Float16 f16x4;

// JAX default gelu: approximate=True (tanh form), libm version
__device__ __forceinline__ float gelu_f(float x) {
    float x3 = x * x * x;
    float inner = 0.7978845608028654f * (x + 0.044715f * x3);
    return 0.5f * x * (1.0f + tanhf(inner));
}

// fast gelu: 0.5x(1+tanh(u)) = x*(1-rcp(exp2(2u*log2e)+1)); ~1ulp exp2/rcp
__device__ __forceinline__ float gelu_fast(float x) {
    const float c1 = 2.3022082232f;     // 2*log2(e)*0.7978845608
    const float c2 = 0.1029432407f;     // c1*0.044715
    float x2 = x * x;
    float t  = x * fmaf(c2, x2, c1);    // 2u*log2(e)
    float E  = __builtin_amdgcn_exp2f(t);          // v_exp_f32
    float r  = __builtin_amdgcn_rcpf(E + 1.0f);    // v_rcp_f32
    return fmaf(-x, r, x);
}

// ---- pass 1: per-chunk LDS histogram over buckets -------------------------
__global__ void __launch_bounds__(256) k_bcount(const int* __restrict__ col,
                                                int* __restrict__ bcnt) {
    __shared__ int cnt[NBKT];
    for (int i = threadIdx.x; i < NBKT; i += 256) cnt[i] = 0;
    __syncthreads();
    int base = blockIdx.x * CHUNK;
    for (int i = threadIdx.x; i < CHUNK; i += 256)
        atomicAdd(&cnt[col[base + i] >> BSHIFT], 1);
    __syncthreads();
    for (int i = threadIdx.x; i < NBKT; i += 256)
        bcnt[i * NCH + blockIdx.x] = cnt[i];      // bucket-major
}

// ---- pass 2a: per-bucket scan of 256 chunk-counts (391 parallel blocks) ---
__global__ void __launch_bounds__(256) k_bscan_local(const int* __restrict__ bcnt,
                                                     int* __restrict__ brel,
                                                     int* __restrict__ btot) {
    __shared__ int sums[256];
    int b = blockIdx.x;
    int t = threadIdx.x;
    int c = bcnt[b * NCH + t];
    sums[t] = c;
    __syncthreads();
    for (int off = 1; off < 256; off <<= 1) {
        int v = 0;
        if (t >= off) v = sums[t - off];
        __syncthreads();
        if (t >= off) sums[t] += v;
        __syncthreads();
    }
    brel[b * NCH + t] = sums[t] - c;
    if (t == 255) btot[b] = sums[255];
}

// ---- pass 2b: scan 391 bucket totals --------------------------------------
__global__ void __launch_bounds__(512) k_bscan_base(const int* __restrict__ btot,
                                                    int* __restrict__ bbase) {
    __shared__ int sums[512];
    int t = threadIdx.x;
    int v0 = (t < NBKT) ? btot[t] : 0;
    sums[t] = v0;
    __syncthreads();
    for (int off = 1; off < 512; off <<= 1) {
        int v = 0;
        if (t >= off) v = sums[t - off];
        __syncthreads();
        if (t >= off) sums[t] += v;
        __syncthreads();
    }
    int excl = sums[t] - v0;
    if (t < NBKT) bbase[t] = excl;
    if (t == NBKT - 1) bbase[NBKT] = excl + v0;   // == N_EDGES
}

// ---- pass 3: scatter edges into bucket segments (LDS cursors) -------------
__global__ void __launch_bounds__(256) k_bscatter(const int* __restrict__ row,
                                                  const int* __restrict__ col,
                                                  const float* __restrict__ ew,
                                                  const int* __restrict__ brel,
                                                  const int* __restrict__ bbase,
                                                  unsigned long long* __restrict__ ebuf) {
    __shared__ int cur[NBKT];
    int ch = blockIdx.x;
    for (int i = threadIdx.x; i < NBKT; i += 256)
        cur[i] = bbase[i] + brel[i * NCH + ch];
    __syncthreads();
    int base = ch * CHUNK;
    for (int i = threadIdx.x; i < CHUNK; i += 256) {
        int c = col[base + i];
        int r = row[base + i];
        float w = ew[base + i];
        int bk = c >> BSHIFT;
        int p = atomicAdd(&cur[bk], 1);           // LDS atomic
        unsigned int hi = ((unsigned)(c & (BNODES - 1)) << 20) | (unsigned)r;
        ebuf[p] = ((unsigned long long)hi << 32) | (unsigned long long)__float_as_uint(w);
    }
}

// ---- pass 4: per-bucket CSR finalize + deg/dinv/y, all in LDS -------------
__global__ void __launch_bounds__(256) k_bbuild(const unsigned long long* __restrict__ ebuf,
                                                const int* __restrict__ bbase,
                                                const float* __restrict__ x,
                                                unsigned long long* __restrict__ csr,
                                                int* __restrict__ offs,
                                                float* __restrict__ dinv,
                                                float* __restrict__ y) {
    __shared__ unsigned long long st[MAXB];
    __shared__ int   cnt[BNODES];
    __shared__ float deg[BNODES];
    __shared__ int   cur[BNODES];
    __shared__ int   sc[BNODES];
    int b = blockIdx.x;
    int t = threadIdx.x;
    int e0 = bbase[b];
    int e1 = bbase[b + 1];
    int len = e1 - e0;
    int sl = min(len, MAXB);
    cnt[t] = 0;
    deg[t] = 0.0f;
    for (int i = t; i < sl; i += 256) st[i] = ebuf[e0 + i];
    __syncthreads();
    for (int i = t; i < len; i += 256) {
        unsigned long long v = (i < MAXB) ? st[i] : ebuf[e0 + i];
        int cl = (int)(v >> 52);            // col_local
        float w = __uint_as_float((unsigned)v);
        atomicAdd(&cnt[cl], 1);
        atomicAdd(&deg[cl], w);
    }
    __syncthreads();
    int c = cnt[t];
    sc[t] = c;
    __syncthreads();
    for (int off = 1; off < 256; off <<= 1) {
        int v = 0;
        if (t >= off) v = sc[t - off];
        __syncthreads();
        if (t >= off) sc[t] += v;
        __syncthreads();
    }
    int loff = sc[t] - c;                   // exclusive prefix within bucket
    cur[t] = loff;
    int node = (b << BSHIFT) + t;
    if (node < N_NODES) {
        offs[node] = e0 + loff;
        float di = rsqrtf(deg[t] + 1.0f);   // +1 = self-loop weight
        dinv[node] = di;
        y[node] = di * x[node];
    }
    if (b == 0 && t == 0) offs[N_NODES] = N_EDGES;
    __syncthreads();
    for (int i = t; i < len; i += 256) {
        unsigned long long v = (i < MAXB) ? st[i] : ebuf[e0 + i];
        int cl = (int)(v >> 52);
        int p = atomicAdd(&cur[cl], 1);     // LDS atomic
        csr[e0 + p] = v;
    }
}

// ---- pass 5: layer-1 scalar agg (per-thread node) -> s1 -------------------
__global__ void __launch_bounds__(256) k_s1(const float* __restrict__ y,
                                            const float* __restrict__ dinv,
                                            const int* __restrict__ offs,
                                            const unsigned long long* __restrict__ csr,
                                            float* __restrict__ s1) {
    int c = blockIdx.x * 256 + threadIdx.x;
    if (c >= N_NODES) return;
    int e0 = offs[c], e1 = offs[c + 1];
    float s = y[c];
    for (int j = e0; j < e1; j++) {
        unsigned long long v = csr[j];
        int src = (int)((v >> 32) & 0xFFFFF);
        float w = __uint_as_float((unsigned)v);
        s = fmaf(w, y[src], s);
    }
    s1[c] = s * dinv[c];
}

// ---- pass 6: h1h[c,f] = fp16( dinv_c * gelu(s1_c*W1_f + b1_f) ) -----------
// thread -> 4 features; grid covers N_NODES*16 threads exactly
__global__ void __launch_bounds__(256) k_h1(const float* __restrict__ s1,
                                            const float* __restrict__ dinv,
                                            const float* __restrict__ W1,
                                            const float* __restrict__ b1,
                                            f16* __restrict__ h1h) {
    int i = blockIdx.x * 256 + threadIdx.x;
    int c  = i >> 4;
    int f4 = (i & 15) << 2;
    float s = s1[c], di = dinv[c];
    const float4 w = *(const float4*)(W1 + f4);
    const float4 bb = *(const float4*)(b1 + f4);
    f16x4 o;
    o.x = (f16)(di * gelu_fast(fmaf(s, w.x, bb.x)));
    o.y = (f16)(di * gelu_fast(fmaf(s, w.y, bb.y)));
    o.z = (f16)(di * gelu_fast(fmaf(s, w.z, bb.z)));
    o.w = (f16)(di * gelu_fast(fmaf(s, w.w, bb.w)));
    *(f16x4*)(h1h + (size_t)c * F + f4) = o;
}

// ---- pass 7: layer-2 agg: gather fp16 rows; 4 nodes/wave, 16 lanes x 4 feat
// a1[c,f] = dinv_c * ( sum_e ew_e * h1h[src_e][f] + h1h[c][f] )
__global__ void __launch_bounds__(256) k_agg(const unsigned long long* __restrict__ csr,
                                             const int* __restrict__ offs,
                                             const f16* __restrict__ h1h,
                                             const float* __restrict__ dinv,
                                             float* __restrict__ a1) {
    int lane = threadIdx.x & 63;
    int wave = (blockIdx.x * 256 + threadIdx.x) >> 6;
    int node = wave * 4 + (lane >> 4);               // grid exact: 6250 blocks
    int l4 = (lane & 15) * 4;
    int e0 = offs[node], e1 = offs[node + 1];
    float4 a = make_float4(0.f, 0.f, 0.f, 0.f);
    float4 b = make_float4(0.f, 0.f, 0.f, 0.f);
    int j = e0;
    for (; j + 1 < e1; j += 2) {
        unsigned long long v0 = csr[j], v1 = csr[j + 1];
        const f16x4 r0 = *(const f16x4*)(h1h + (size_t)((v0 >> 32) & 0xFFFFF) * F + l4);
        const f16x4 r1 = *(const f16x4*)(h1h + (size_t)((v1 >> 32) & 0xFFFFF) * F + l4);
        float w0 = __uint_as_float((unsigned)v0);
        float w1 = __uint_as_float((unsigned)v1);
        a.x = fmaf(w0, (float)r0.x, a.x); a.y = fmaf(w0, (float)r0.y, a.y);
        a.z = fmaf(w0, (float)r0.z, a.z); a.w = fmaf(w0, (float)r0.w, a.w);
        b.x = fmaf(w1, (float)r1.x, b.x); b.y = fmaf(w1, (float)r1.y, b.y);
        b.z = fmaf(w1, (float)r1.z, b.z); b.w = fmaf(w1, (float)r1.w, b.w);
    }
    if (j < e1) {
        unsigned long long v0 = csr[j];
        const f16x4 r0 = *(const f16x4*)(h1h + (size_t)((v0 >> 32) & 0xFFFFF) * F + l4);
        float w0 = __uint_as_float((unsigned)v0);
        a.x = fmaf(w0, (float)r0.x, a.x); a.y = fmaf(w0, (float)r0.y, a.y);
        a.z = fmaf(w0, (float)r0.z, a.z); a.w = fmaf(w0, (float)r0.w, a.w);
    }
    const f16x4 sf = *(const f16x4*)(h1h + (size_t)node * F + l4);
    float di = dinv[node];
    float4 o;
    o.x = di * (a.x + b.x + (float)sf.x);
    o.y = di * (a.y + b.y + (float)sf.y);
    o.z = di * (a.z + b.z + (float)sf.z);
    o.w = di * (a.w + b.w + (float)sf.w);
    *(float4*)(a1 + (size_t)node * F + l4) = o;
}

// ---- pass 8: fused h2 matmul (+bias+gelu) and mean-pool; W2 in VGPRs ------
#define STRIP 32                                   // nodes per wave
__global__ void __launch_bounds__(256) k_h2pool(const float* __restrict__ a1,
                                                const float* __restrict__ W2,
                                                const float* __restrict__ b2,
                                                const int* __restrict__ batch,
                                                float* __restrict__ gsum,
                                                float* __restrict__ gcnt) {
    int lane = threadIdx.x & 63;
    int wv   = threadIdx.x >> 6;
    int gw   = blockIdx.x * 4 + wv;
    int n0 = gw * STRIP;
    if (n0 >= N_NODES) return;
    int n1 = min(n0 + STRIP, N_NODES);
    float w2r[F];                                  // column W2[:,lane] in regs
#pragma unroll
    for (int k = 0; k < F; k++) w2r[k] = W2[k * F + lane];
    float b2f = b2[lane];
    int curg = batch[n0];
    float run = 0.0f;
    int   rl  = 0;
    for (int n = n0; n < n1; n++) {
        int g = batch[n];
        if (g != curg) {
            atomicAdd(&gsum[curg * F + lane], run);
            if (lane == 0) atomicAdd(&gcnt[curg], (float)rl);
            run = 0.0f; rl = 0; curg = g;
        }
        const float4* rowp = (const float4*)(a1 + (size_t)n * F);
        float acc = b2f;
#pragma unroll
        for (int k4 = 0; k4 < F / 4; k4++) {
            float4 r = rowp[k4];                   // uniform address -> broadcast
            acc = fmaf(r.x, w2r[4 * k4 + 0], acc);
            acc = fmaf(r.y, w2r[4 * k4 + 1], acc);
            acc = fmaf(r.z, w2r[4 * k4 + 2], acc);
            acc = fmaf(r.w, w2r[4 * k4 + 3], acc);
        }
        run += gelu_fast(acc);
        rl++;
    }
    atomicAdd(&gsum[curg * F + lane], run);
    if (lane == 0) atomicAdd(&gcnt[curg], (float)rl);
}

// ---- final MLP: one wave per graph ----------------------------------------
__global__ void __launch_bounds__(256) k_final(const float* __restrict__ gsum,
                                               const float* __restrict__ gcnt,
                                               const float* __restrict__ fc1W,
                                               const float* __restrict__ fc1b,
                                               const float* __restrict__ fc2W,
                                               const float* __restrict__ fc2b,
                                               float* __restrict__ out) {
    __shared__ float sm[4][F];
    int lane = threadIdx.x & 63;
    int wv   = threadIdx.x >> 6;
    int g = blockIdx.x * 4 + wv;
    if (g >= N_GRAPHS) return;
    float c = gcnt[g];
    float m = gsum[g * F + lane] / fmaxf(c, 1.0f);
    sm[wv][lane] = m;
    float o = 0.0f;
    if (lane < 32) {
        float acc = fc1b[lane];
#pragma unroll
        for (int k = 0; k < F; k++) acc = fmaf(sm[wv][k], fc1W[k * 32 + lane], acc);
        o = gelu_f(acc) * fc2W[lane];
    }
    for (int off = 32; off; off >>= 1) o += __shfl_down(o, off);
    if (lane == 0) out[g] = o + fc2b[0];
}

// ---------------------------------------------------------------------------

extern "C" void kernel_launch(void* const* d_in, const int* in_sizes, int n_in,
                              void* d_out, int out_size, void* d_ws, size_t ws_size,
                              hipStream_t stream) {
    const float* x    = (const float*)d_in[0];
    const int*   ei   = (const int*)  d_in[1];   // [2, E]
    const float* ea   = (const float*)d_in[2];
    const int*   bat  = (const int*)  d_in[3];
    const float* W1   = (const float*)d_in[4];
    const float* b1   = (const float*)d_in[5];
    const float* W2   = (const float*)d_in[6];
    const float* b2   = (const float*)d_in[7];
    const float* fc1W = (const float*)d_in[8];
    const float* fc1b = (const float*)d_in[9];
    const float* fc2W = (const float*)d_in[10];
    const float* fc2b = (const float*)d_in[11];
    float* out = (float*)d_out;

    const int* row = ei;
    const int* col = ei + N_EDGES;

    size_t off = 0;
    auto alloc = [&](size_t bytes) -> void* {
        void* p = (char*)d_ws + off;
        off = (off + bytes + 255) & ~(size_t)255;
        return p;
    };
    int*   bcnt  = (int*)alloc((size_t)NBKT * NCH * 4);            // 400 KB
    int*   brel  = (int*)alloc((size_t)NBKT * NCH * 4);            // 400 KB
    int*   btot  = (int*)alloc((size_t)NBKT * 4);
    int*   bbase = (int*)alloc((size_t)(NBKT + 1) * 4);
    unsigned long long* ebuf = (unsigned long long*)alloc((size_t)N_EDGES * 8); // 25.6 MB
    unsigned long long* csr  = (unsigned long long*)alloc((size_t)N_EDGES * 8); // 25.6 MB
    int*   offs = (int*)  alloc((size_t)(N_NODES + 1) * 4);
    float* dinv = (float*)alloc((size_t)N_NODES * 4);
    float* yv   = (float*)alloc((size_t)N_NODES * 4);
    float* s1   = (float*)alloc((size_t)N_NODES * 4);
    f16*   h1h  = (f16*)  alloc((size_t)N_NODES * F * 2);          // 12.8 MB fp16
    float* a1   = (float*)ebuf;                                    // alias: ebuf dead after k_bbuild
    float* gsum = (float*)alloc((size_t)N_GRAPHS * F * 4);
    float* gcnt = (float*)alloc((size_t)N_GRAPHS * 4);
    (void)ws_size; (void)n_in; (void)in_sizes; (void)out_size;

    (void)hipMemsetAsync(gsum, 0, N_GRAPHS * F * 4, stream);
    (void)hipMemsetAsync(gcnt, 0, N_GRAPHS * 4,     stream);

    k_bcount     <<<NCH, 256, 0, stream>>>(col, bcnt);
    k_bscan_local<<<NBKT, 256, 0, stream>>>(bcnt, brel, btot);
    k_bscan_base <<<1, 512, 0, stream>>>(btot, bbase);
    k_bscatter   <<<NCH, 256, 0, stream>>>(row, col, ea, brel, bbase, ebuf);
    k_bbuild     <<<NBKT, 256, 0, stream>>>(ebuf, bbase, x, csr, offs, dinv, yv);
    k_s1         <<<(N_NODES + 255) / 256, 256, 0, stream>>>(yv, dinv, offs, csr, s1);
    k_h1         <<<(N_NODES * 16) / 256, 256, 0, stream>>>(s1, dinv, W1, b1, h1h);
    k_agg        <<<(N_NODES * 16) / 256, 256, 0, stream>>>(csr, offs, h1h, dinv, a1);
    {
        int waves = (N_NODES + STRIP - 1) / STRIP;        // 3125
        k_h2pool <<<(waves + 3) / 4, 256, 0, stream>>>(a1, W2, b2, bat, gsum, gcnt);
    }
    k_final      <<<(N_GRAPHS + 3) / 4, 256, 0, stream>>>(gsum, gcnt, fc1W, fc1b, fc2W, fc2b, out);
}

// Round 9
// 320.533 us; speedup vs baseline: 5.4882x; 1.2128x over previous
//
#include <hip/hip_runtime.h>
#include <math.h>

#define N_NODES  100000
#define N_EDGES  3200000
#define N_GRAPHS 256
#define F        64

// bucketed counting sort params
#define BSHIFT   8
#define BNODES   256                    // nodes per bucket
#define NBKT     391                    // ceil(N_NODES / BNODES)
#define NCH      1024                   // edge chunks (4 blocks/CU for sort passes)
#define CHUNK    3125                   // edges per chunk (NCH*CHUNK == N_EDGES)
#define MAXB     9000                   // LDS-staged edges per bucket (avg 8192, sd ~90)

typedef _Float16 f16;
typedef __attribute__((ext_vector_type(4))) _Float16 f16x4;
typedef __attribute__((ext_vector_type(8))) _Float16 f16x8;

// JAX default gelu: approximate=True (tanh form), libm version
__device__ __forceinline__ float gelu_f(float x) {
    float x3 = x * x * x;
    float inner = 0.7978845608028654f * (x + 0.044715f * x3);
    return 0.5f * x * (1.0f + tanhf(inner));
}

// fast gelu: 0.5x(1+tanh(u)) = x*(1-rcp(exp2(2u*log2e)+1)); ~1ulp exp2/rcp
__device__ __forceinline__ float gelu_fast(float x) {
    const float c1 = 2.3022082232f;     // 2*log2(e)*0.7978845608
    const float c2 = 0.1029432407f;     // c1*0.044715
    float x2 = x * x;
    float t  = x * fmaf(c2, x2, c1);
    float E  = __builtin_amdgcn_exp2f(t);          // v_exp_f32
    float r  = __builtin_amdgcn_rcpf(E + 1.0f);    // v_rcp_f32
    return fmaf(-x, r, x);
}

// ---- pass 1: per-chunk LDS histogram over buckets -------------------------
__global__ void __launch_bounds__(512) k_bcount(const int* __restrict__ col,
                                                int* __restrict__ bcnt) {
    __shared__ int cnt[NBKT];
    for (int i = threadIdx.x; i < NBKT; i += 512) cnt[i] = 0;
    __syncthreads();
    int base = blockIdx.x * CHUNK;
    for (int i = threadIdx.x; i < CHUNK; i += 512)
        atomicAdd(&cnt[col[base + i] >> BSHIFT], 1);
    __syncthreads();
    for (int i = threadIdx.x; i < NBKT; i += 512)
        bcnt[i * NCH + blockIdx.x] = cnt[i];      // bucket-major
}

// ---- pass 2a: per-bucket scan of 1024 chunk-counts (391 parallel blocks) --
__global__ void __launch_bounds__(512) k_bscan_local(const int* __restrict__ bcnt,
                                                     int* __restrict__ brel,
                                                     int* __restrict__ btot) {
    __shared__ int sums[512];
    int b = blockIdx.x;
    int t = threadIdx.x;
    int i0 = b * NCH + 2 * t;
    int c0 = bcnt[i0], c1 = bcnt[i0 + 1];
    int s = c0 + c1;
    sums[t] = s;
    __syncthreads();
    for (int off = 1; off < 512; off <<= 1) {
        int v = 0;
        if (t >= off) v = sums[t - off];
        __syncthreads();
        if (t >= off) sums[t] += v;
        __syncthreads();
    }
    int excl = sums[t] - s;
    brel[i0]     = excl;
    brel[i0 + 1] = excl + c0;
    if (t == 511) btot[b] = sums[511];
}

// ---- pass 2b: scan 391 bucket totals; also zero gsum/gcnt -----------------
__global__ void __launch_bounds__(512) k_bscan_base(const int* __restrict__ btot,
                                                    int* __restrict__ bbase,
                                                    float* __restrict__ gsum,
                                                    float* __restrict__ gcnt) {
    __shared__ int sums[512];
    int t = threadIdx.x;
    for (int i = t; i < N_GRAPHS * F; i += 512) gsum[i] = 0.0f;
    if (t < N_GRAPHS) gcnt[t] = 0.0f;
    int v0 = (t < NBKT) ? btot[t] : 0;
    sums[t] = v0;
    __syncthreads();
    for (int off = 1; off < 512; off <<= 1) {
        int v = 0;
        if (t >= off) v = sums[t - off];
        __syncthreads();
        if (t >= off) sums[t] += v;
        __syncthreads();
    }
    int excl = sums[t] - v0;
    if (t < NBKT) bbase[t] = excl;
    if (t == NBKT - 1) bbase[NBKT] = excl + v0;   // == N_EDGES
}

// ---- pass 3: scatter edges into bucket segments (LDS cursors) -------------
__global__ void __launch_bounds__(512) k_bscatter(const int* __restrict__ row,
                                                  const int* __restrict__ col,
                                                  const float* __restrict__ ew,
                                                  const int* __restrict__ brel,
                                                  const int* __restrict__ bbase,
                                                  unsigned long long* __restrict__ ebuf) {
    __shared__ int cur[NBKT];
    int ch = blockIdx.x;
    for (int i = threadIdx.x; i < NBKT; i += 512)
        cur[i] = bbase[i] + brel[i * NCH + ch];
    __syncthreads();
    int base = ch * CHUNK;
    for (int i = threadIdx.x; i < CHUNK; i += 512) {
        int c = col[base + i];
        int r = row[base + i];
        float w = ew[base + i];
        int bk = c >> BSHIFT;
        int p = atomicAdd(&cur[bk], 1);           // LDS atomic
        unsigned int hi = ((unsigned)(c & (BNODES - 1)) << 20) | (unsigned)r;
        ebuf[p] = ((unsigned long long)hi << 32) | (unsigned long long)__float_as_uint(w);
    }
}

// ---- pass 4: per-bucket CSR finalize + deg/dinv/y, all in LDS -------------
__global__ void __launch_bounds__(512) k_bbuild(const unsigned long long* __restrict__ ebuf,
                                                const int* __restrict__ bbase,
                                                const float* __restrict__ x,
                                                unsigned long long* __restrict__ csr,
                                                int* __restrict__ offs,
                                                float* __restrict__ dinv,
                                                float* __restrict__ y) {
    __shared__ unsigned long long st[MAXB];
    __shared__ int   cnt[BNODES];
    __shared__ float deg[BNODES];
    __shared__ int   cur[BNODES];
    __shared__ int   sc[BNODES];
    int b = blockIdx.x;
    int t = threadIdx.x;
    int e0 = bbase[b];
    int e1 = bbase[b + 1];
    int len = e1 - e0;
    int sl = min(len, MAXB);
    if (t < BNODES) { cnt[t] = 0; deg[t] = 0.0f; }
    for (int i = t; i < sl; i += 512) st[i] = ebuf[e0 + i];
    __syncthreads();
    for (int i = t; i < len; i += 512) {
        unsigned long long v = (i < MAXB) ? st[i] : ebuf[e0 + i];
        int cl = (int)(v >> 52);            // col_local
        float w = __uint_as_float((unsigned)v);
        atomicAdd(&cnt[cl], 1);
        atomicAdd(&deg[cl], w);
    }
    __syncthreads();
    int c = 0;
    if (t < BNODES) { c = cnt[t]; sc[t] = c; }
    __syncthreads();
    for (int off = 1; off < BNODES; off <<= 1) {
        int v = 0;
        if (t >= off && t < BNODES) v = sc[t - off];
        __syncthreads();
        if (t >= off && t < BNODES) sc[t] += v;
        __syncthreads();
    }
    if (t < BNODES) {
        int loff = sc[t] - c;               // exclusive prefix within bucket
        cur[t] = loff;
        int node = (b << BSHIFT) + t;
        if (node < N_NODES) {
            offs[node] = e0 + loff;
            float di = rsqrtf(deg[t] + 1.0f);   // +1 = self-loop weight
            dinv[node] = di;
            y[node] = di * x[node];
        }
        if (b == 0 && t == 0) offs[N_NODES] = N_EDGES;
    }
    __syncthreads();
    for (int i = t; i < len; i += 512) {
        unsigned long long v = (i < MAXB) ? st[i] : ebuf[e0 + i];
        int cl = (int)(v >> 52);
        int p = atomicAdd(&cur[cl], 1);     // LDS atomic
        csr[e0 + p] = v;
    }
}

// ---- pass 5: fused layer-1 scalar agg (bucket LDS atomics) + h1 expand ----
// s1[c] = dinv_c*(sum ew*y[src] + y[c]);  h1h[c,f] = fp16(dinv_c*gelu(s1*W1+b1))
__global__ void __launch_bounds__(512) k_s1h1(const unsigned long long* __restrict__ ebuf,
                                              const int* __restrict__ bbase,
                                              const float* __restrict__ y,
                                              const float* __restrict__ dinv,
                                              const float* __restrict__ W1,
                                              const float* __restrict__ b1,
                                              f16* __restrict__ h1h) {
    __shared__ float s[BNODES];
    __shared__ float dv[BNODES];
    int b = blockIdx.x, t = threadIdx.x;
    if (t < BNODES) s[t] = 0.0f;
    __syncthreads();
    int e0 = bbase[b], e1 = bbase[b + 1];
    for (int i = e0 + t; i < e1; i += 512) {
        unsigned long long v = ebuf[i];
        int src = (int)((v >> 32) & 0xFFFFF);
        float w = __uint_as_float((unsigned)v);
        atomicAdd(&s[(int)(v >> 52)], w * y[src]);   // y gather: 400KB, L2-resident
    }
    __syncthreads();
    if (t < BNODES) {
        int node = (b << BSHIFT) + t;
        float s1v = 0.0f, di = 0.0f;
        if (node < N_NODES) {
            di = dinv[node];
            s1v = (s[t] + y[node]) * di;
        }
        s[t] = s1v;
        dv[t] = di;
    }
    __syncthreads();
    // h1 expansion: item = (node_local, f4); coalesced f16x4 stores
    for (int idx = t; idx < BNODES * 16; idx += 512) {
        int nl = idx >> 4;
        int node = (b << BSHIFT) + nl;
        if (node >= N_NODES) continue;
        int f4 = (idx & 15) << 2;
        float s1v = s[nl], di = dv[nl];
        const float4 w  = *(const float4*)(W1 + f4);
        const float4 bb = *(const float4*)(b1 + f4);
        f16x4 o;
        o.x = (f16)(di * gelu_fast(fmaf(s1v, w.x, bb.x)));
        o.y = (f16)(di * gelu_fast(fmaf(s1v, w.y, bb.y)));
        o.z = (f16)(di * gelu_fast(fmaf(s1v, w.z, bb.z)));
        o.w = (f16)(di * gelu_fast(fmaf(s1v, w.w, bb.w)));
        *(f16x4*)(h1h + (size_t)node * F + f4) = o;
    }
}

// ---- pass 6: layer-2 agg: gather fp16 rows; 4 nodes/wave, 16 lanes x 4 feat
// a1h[c,f] = fp16( dinv_c * ( sum_e ew_e * h1h[src_e][f] + h1h[c][f] ) )
__global__ void __launch_bounds__(256) k_agg(const unsigned long long* __restrict__ csr,
                                             const int* __restrict__ offs,
                                             const f16* __restrict__ h1h,
                                             const float* __restrict__ dinv,
                                             f16* __restrict__ a1h) {
    int lane = threadIdx.x & 63;
    int wave = (blockIdx.x * 256 + threadIdx.x) >> 6;
    int node = wave * 4 + (lane >> 4);               // grid exact: 6250 blocks
    int l4 = (lane & 15) * 4;
    int e0 = offs[node], e1 = offs[node + 1];
    float4 a = make_float4(0.f, 0.f, 0.f, 0.f);
    float4 b = make_float4(0.f, 0.f, 0.f, 0.f);
    int j = e0;
    for (; j + 1 < e1; j += 2) {
        unsigned long long v0 = csr[j], v1 = csr[j + 1];
        const f16x4 r0 = *(const f16x4*)(h1h + (size_t)((v0 >> 32) & 0xFFFFF) * F + l4);
        const f16x4 r1 = *(const f16x4*)(h1h + (size_t)((v1 >> 32) & 0xFFFFF) * F + l4);
        float w0 = __uint_as_float((unsigned)v0);
        float w1 = __uint_as_float((unsigned)v1);
        a.x = fmaf(w0, (float)r0.x, a.x); a.y = fmaf(w0, (float)r0.y, a.y);
        a.z = fmaf(w0, (float)r0.z, a.z); a.w = fmaf(w0, (float)r0.w, a.w);
        b.x = fmaf(w1, (float)r1.x, b.x); b.y = fmaf(w1, (float)r1.y, b.y);
        b.z = fmaf(w1, (float)r1.z, b.z); b.w = fmaf(w1, (float)r1.w, b.w);
    }
    if (j < e1) {
        unsigned long long v0 = csr[j];
        const f16x4 r0 = *(const f16x4*)(h1h + (size_t)((v0 >> 32) & 0xFFFFF) * F + l4);
        float w0 = __uint_as_float((unsigned)v0);
        a.x = fmaf(w0, (float)r0.x, a.x); a.y = fmaf(w0, (float)r0.y, a.y);
        a.z = fmaf(w0, (float)r0.z, a.z); a.w = fmaf(w0, (float)r0.w, a.w);
    }
    const f16x4 sf = *(const f16x4*)(h1h + (size_t)node * F + l4);
    float di = dinv[node];
    f16x4 o;
    o.x = (f16)(di * (a.x + b.x + (float)sf.x));
    o.y = (f16)(di * (a.y + b.y + (float)sf.y));
    o.z = (f16)(di * (a.z + b.z + (float)sf.z));
    o.w = (f16)(di * (a.w + b.w + (float)sf.w));
    *(f16x4*)(a1h + (size_t)node * F + l4) = o;
}

// ---- pass 7: fused h2 matmul (+bias+gelu) and mean-pool; W2 in VGPRs ------
#define STRIP 32                                   // nodes per wave
__global__ void __launch_bounds__(256) k_h2pool(const f16* __restrict__ a1h,
                                                const float* __restrict__ W2,
                                                const float* __restrict__ b2,
                                                const int* __restrict__ batch,
                                                float* __restrict__ gsum,
                                                float* __restrict__ gcnt) {
    int lane = threadIdx.x & 63;
    int wv   = threadIdx.x >> 6;
    int gw   = blockIdx.x * 4 + wv;
    int n0 = gw * STRIP;
    if (n0 >= N_NODES) return;
    int n1 = min(n0 + STRIP, N_NODES);
    float w2r[F];                                  // column W2[:,lane] in regs
#pragma unroll
    for (int k = 0; k < F; k++) w2r[k] = W2[k * F + lane];
    float b2f = b2[lane];
    int curg = batch[n0];
    float run = 0.0f;
    int   rl  = 0;
    for (int n = n0; n < n1; n++) {
        int g = batch[n];
        if (g != curg) {
            atomicAdd(&gsum[curg * F + lane], run);
            if (lane == 0) atomicAdd(&gcnt[curg], (float)rl);
            run = 0.0f; rl = 0; curg = g;
        }
        const f16x8* rowp = (const f16x8*)(a1h + (size_t)n * F);
        float acc = b2f;
#pragma unroll
        for (int k8 = 0; k8 < F / 8; k8++) {
            f16x8 r = rowp[k8];                    // uniform 16B -> broadcast
            acc = fmaf((float)r[0], w2r[8 * k8 + 0], acc);
            acc = fmaf((float)r[1], w2r[8 * k8 + 1], acc);
            acc = fmaf((float)r[2], w2r[8 * k8 + 2], acc);
            acc = fmaf((float)r[3], w2r[8 * k8 + 3], acc);
            acc = fmaf((float)r[4], w2r[8 * k8 + 4], acc);
            acc = fmaf((float)r[5], w2r[8 * k8 + 5], acc);
            acc = fmaf((float)r[6], w2r[8 * k8 + 6], acc);
            acc = fmaf((float)r[7], w2r[8 * k8 + 7], acc);
        }
        run += gelu_fast(acc);
        rl++;
    }
    atomicAdd(&gsum[curg * F + lane], run);
    if (lane == 0) atomicAdd(&gcnt[curg], (float)rl);
}

// ---- final MLP: one wave per graph ----------------------------------------
__global__ void __launch_bounds__(256) k_final(const float* __restrict__ gsum,
                                               const float* __restrict__ gcnt,
                                               const float* __restrict__ fc1W,
                                               const float* __restrict__ fc1b,
                                               const float* __restrict__ fc2W,
                                               const float* __restrict__ fc2b,
                                               float* __restrict__ out) {
    __shared__ float sm[4][F];
    int lane = threadIdx.x & 63;
    int wv   = threadIdx.x >> 6;
    int g = blockIdx.x * 4 + wv;
    if (g >= N_GRAPHS) return;
    float c = gcnt[g];
    float m = gsum[g * F + lane] / fmaxf(c, 1.0f);
    sm[wv][lane] = m;
    float o = 0.0f;
    if (lane < 32) {
        float acc = fc1b[lane];
#pragma unroll
        for (int k = 0; k < F; k++) acc = fmaf(sm[wv][k], fc1W[k * 32 + lane], acc);
        o = gelu_f(acc) * fc2W[lane];
    }
    for (int off = 32; off; off >>= 1) o += __shfl_down(o, off);
    if (lane == 0) out[g] = o + fc2b[0];
}

// ---------------------------------------------------------------------------

extern "C" void kernel_launch(void* const* d_in, const int* in_sizes, int n_in,
                              void* d_out, int out_size, void* d_ws, size_t ws_size,
                              hipStream_t stream) {
    const float* x    = (const float*)d_in[0];
    const int*   ei   = (const int*)  d_in[1];   // [2, E]
    const float* ea   = (const float*)d_in[2];
    const int*   bat  = (const int*)  d_in[3];
    const float* W1   = (const float*)d_in[4];
    const float* b1   = (const float*)d_in[5];
    const float* W2   = (const float*)d_in[6];
    const float* b2   = (const float*)d_in[7];
    const float* fc1W = (const float*)d_in[8];
    const float* fc1b = (const float*)d_in[9];
    const float* fc2W = (const float*)d_in[10];
    const float* fc2b = (const float*)d_in[11];
    float* out = (float*)d_out;

    const int* row = ei;
    const int* col = ei + N_EDGES;

    size_t off = 0;
    auto alloc = [&](size_t bytes) -> void* {
        void* p = (char*)d_ws + off;
        off = (off + bytes + 255) & ~(size_t)255;
        return p;
    };
    int*   bcnt  = (int*)alloc((size_t)NBKT * NCH * 4);            // 1.6 MB
    int*   brel  = (int*)alloc((size_t)NBKT * NCH * 4);            // 1.6 MB
    int*   btot  = (int*)alloc((size_t)NBKT * 4);
    int*   bbase = (int*)alloc((size_t)(NBKT + 1) * 4);
    unsigned long long* ebuf = (unsigned long long*)alloc((size_t)N_EDGES * 8); // 25.6 MB
    unsigned long long* csr  = (unsigned long long*)alloc((size_t)N_EDGES * 8); // 25.6 MB
    int*   offs = (int*)  alloc((size_t)(N_NODES + 1) * 4);
    float* dinv = (float*)alloc((size_t)N_NODES * 4);
    float* yv   = (float*)alloc((size_t)N_NODES * 4);
    f16*   h1h  = (f16*)  alloc((size_t)N_NODES * F * 2);          // 12.8 MB fp16
    f16*   a1h  = (f16*)ebuf;                        // alias: ebuf dead after k_s1h1
    float* gsum = (float*)alloc((size_t)N_GRAPHS * F * 4);
    float* gcnt = (float*)alloc((size_t)N_GRAPHS * 4);
    (void)ws_size; (void)n_in; (void)in_sizes; (void)out_size;

    k_bcount     <<<NCH, 512, 0, stream>>>(col, bcnt);
    k_bscan_local<<<NBKT, 512, 0, stream>>>(bcnt, brel, btot);
    k_bscan_base <<<1, 512, 0, stream>>>(btot, bbase, gsum, gcnt);
    k_bscatter   <<<NCH, 512, 0, stream>>>(row, col, ea, brel, bbase, ebuf);
    k_bbuild     <<<NBKT, 512, 0, stream>>>(ebuf, bbase, x, csr, offs, dinv, yv);
    k_s1h1       <<<NBKT, 512, 0, stream>>>(ebuf, bbase, yv, dinv, W1, b1, h1h);
    k_agg        <<<(N_NODES * 16) / 256, 256, 0, stream>>>(csr, offs, h1h, dinv, a1h);
    {
        int waves = (N_NODES + STRIP - 1) / STRIP;        // 3125
        k_h2pool <<<(waves + 3) / 4, 256, 0, stream>>>(a1h, W2, b2, bat, gsum, gcnt);
    }
    k_final      <<<(N_GRAPHS + 3) / 4, 256, 0, stream>>>(gsum, gcnt, fc1W, fc1b, fc2W, fc2b, out);
}